// Round 19
// baseline (156.751 us; speedup 1.0000x reference)
//
// GCNEncoder MI355X kernel — v16: k_fuse split into k_gemm1 (reg-staged A-loads,
// launch_bounds(512,8) -> 8 float4 in flight vs v15's 2 at VGPR=32) and
// k_bscatter (unchanged role) for per-role counter attribution. Rest = v15.
#include <hip/hip_runtime.h>

#define NN 100000
#define NE 1600000
#define NB 391            // ceil(NN/256) buckets of 256 nodes (bucket = dst >> 8)
#define CHUNK 4096
#define NCHUNK 391        // ceil(NE/CHUNK)

typedef __attribute__((ext_vector_type(8))) short short8_t;
typedef __attribute__((ext_vector_type(4))) float float4_t;

// ---- bf16 helpers (RNE pack, bit-op unpack) ----
__device__ inline unsigned short f2bf(float f) {
    unsigned int u = __float_as_uint(f);
    unsigned int r = u + 0x7fffu + ((u >> 16) & 1u);
    return (unsigned short)(r >> 16);
}
__device__ inline float bf_lo(unsigned int u) { return __uint_as_float(u << 16); }
__device__ inline float bf_hi(unsigned int u) { return __uint_as_float(u & 0xffff0000u); }

// ---------------- prologue: W1^T, [W2|W3]^T ----------------
__global__ __launch_bounds__(256) void k_pre(const float* __restrict__ W1,
                                             const float* __restrict__ W2,
                                             const float* __restrict__ W3,
                                             unsigned short* __restrict__ wtb,
                                             unsigned short* __restrict__ wt2) {
    int f = blockIdx.x * 256 + threadIdx.x;      // 0..8191
    int c = f >> 7, k = f & 127;
    wtb[f] = f2bf(W1[k * 64 + c]);               // wtb[c][k] = W1[k][c]
    if (f < 4096) {                              // wt2[c][k] = Wc[k][c], Wc=[W2|W3]
        int c2 = f >> 6, k2 = f & 63;
        float v = (c2 < 32) ? W2[k2 * 32 + c2] : W3[k2 * 32 + (c2 - 32)];
        wt2[f] = f2bf(v);
    }
}

// ---------------- per-chunk histogram: hist2d[c][b] ----------------
__global__ __launch_bounds__(256) void k_chist(const int* __restrict__ dst,
                                               int* __restrict__ hist2d) {
    __shared__ int lh[NB];
    int c = blockIdx.x, t = threadIdx.x;
    for (int i = t; i < NB; i += 256) lh[i] = 0;
    __syncthreads();
    int e0 = c * CHUNK, e1 = min(e0 + CHUNK, NE);
    for (int e = e0 + t; e < e1; e += 256)
        atomicAdd(&lh[dst[e] >> 8], 1);
    __syncthreads();
    for (int i = t; i < NB; i += 256) hist2d[c * NB + i] = lh[i];
}

// ---------------- per-bucket scan over chunks: base2d[c][b], colsum[b] ----------------
__global__ __launch_bounds__(256) void k_scancol(const int* __restrict__ hist2d,
                                                 int* __restrict__ base2d,
                                                 int* __restrict__ colsum) {
    __shared__ int sh[256];
    int b = blockIdx.x, t = threadIdx.x;
    int base = t * 2;                       // chunks base, base+1
    int v0 = (base + 0 < NCHUNK) ? hist2d[(base + 0) * NB + b] : 0;
    int v1 = (base + 1 < NCHUNK) ? hist2d[(base + 1) * NB + b] : 0;
    int tsum = v0 + v1;
    sh[t] = tsum;
    __syncthreads();
    for (int d = 1; d < 256; d <<= 1) {
        int x = (t >= d) ? sh[t - d] : 0;
        __syncthreads();
        sh[t] += x;
        __syncthreads();
    }
    int excl = sh[t] - tsum;
    if (base + 0 < NCHUNK) base2d[(base + 0) * NB + b] = excl;
    if (base + 1 < NCHUNK) base2d[(base + 1) * NB + b] = excl + v0;
    if (t == 255) colsum[b] = sh[255];
}

// ---------------- bucket scan: boff ----------------
__global__ __launch_bounds__(256) void k_scanb(const int* __restrict__ colsum,
                                               int* __restrict__ boff) {
    __shared__ int sh[256];
    int t = threadIdx.x;
    int base = t * 2;
    int v0 = (base + 0 < NB) ? colsum[base + 0] : 0;
    int v1 = (base + 1 < NB) ? colsum[base + 1] : 0;
    int tsum = v0 + v1;
    sh[t] = tsum;
    __syncthreads();
    for (int d = 1; d < 256; d <<= 1) {
        int x = (t >= d) ? sh[t - d] : 0;
        __syncthreads();
        sh[t] += x;
        __syncthreads();
    }
    int excl = sh[t] - tsum;
    if (base + 0 < NB) boff[base + 0] = excl;
    if (base + 1 < NB) boff[base + 1] = excl + v0;
    if (t == 255) boff[NB] = sh[255];   // == NE
}

// ---------------- GEMM1 (MFMA, LDS-free, reg-staged A): t1b = bf16(x @ W1) ----------------
__global__ __launch_bounds__(512, 8) void k_gemm1(const float* __restrict__ x,
                                                  const unsigned short* __restrict__ wtb,
                                                  unsigned short* __restrict__ t1b) {
    const int tile = blockIdx.x;
    const int row0 = tile * 128;
    const int nrows = min(128, NN - row0);
    const int t = threadIdx.x;
    const int w = t >> 6, l = t & 63;
    const int m15 = l & 15, kg = l >> 4;

    int ra = min(row0 + w * 16 + m15, NN - 1);   // clamped tail row
    const float4* xa = (const float4*)(x + (size_t)ra * 128) + kg * 2;

    // stage ALL 8 x-loads into registers first -> 8 loads in flight per wave
    float4 f[8];
    #pragma unroll
    for (int ks = 0; ks < 4; ++ks) {
        f[2 * ks]     = xa[ks * 8];
        f[2 * ks + 1] = xa[ks * 8 + 1];
    }

    float4_t acc[4];
    #pragma unroll
    for (int cb = 0; cb < 4; ++cb) acc[cb] = (float4_t){0.f, 0.f, 0.f, 0.f};

    #pragma unroll
    for (int ks = 0; ks < 4; ++ks) {
        float4 f0 = f[2 * ks], f1 = f[2 * ks + 1];
        short8_t a;
        a[0] = (short)f2bf(f0.x); a[1] = (short)f2bf(f0.y);
        a[2] = (short)f2bf(f0.z); a[3] = (short)f2bf(f0.w);
        a[4] = (short)f2bf(f1.x); a[5] = (short)f2bf(f1.y);
        a[6] = (short)f2bf(f1.z); a[7] = (short)f2bf(f1.w);
        #pragma unroll
        for (int cb = 0; cb < 4; ++cb) {
            short8_t bb = *(const short8_t*)(wtb + (cb * 16 + m15) * 128 + ks * 32 + kg * 8);
            acc[cb] = __builtin_amdgcn_mfma_f32_16x16x32_bf16(a, bb, acc[cb], 0, 0, 0);
        }
    }

    #pragma unroll
    for (int r = 0; r < 4; ++r) {
        int lrow = w * 16 + kg * 4 + r;
        if (lrow < nrows) {
            size_t grow = (size_t)(row0 + lrow);
            #pragma unroll
            for (int cb = 0; cb < 4; ++cb)
                t1b[grow * 64 + cb * 16 + m15] = f2bf(acc[cb][r]);
        }
    }
}

// ---------------- bscatter: chunked scatter with precomputed atomic-free bases ----------------
__global__ __launch_bounds__(512) void k_bscatter(const int* __restrict__ src,
                                                  const int* __restrict__ dst,
                                                  const int* __restrict__ base2d,
                                                  const int* __restrict__ boff,
                                                  unsigned int* __restrict__ pairs) {
    __shared__ int lbase[NB];
    __shared__ int lh[NB];
    const int c = blockIdx.x;
    const int t = threadIdx.x;
    int e0 = c * CHUNK;
    int e1 = min(e0 + CHUNK, NE);
    for (int i = t; i < NB; i += 512) {
        lbase[i] = base2d[c * NB + i] + boff[i];
        lh[i] = 0;
    }
    __syncthreads();
    for (int e = e0 + t; e < e1; e += 512) {
        int d = dst[e];
        int bk = d >> 8;
        int r = atomicAdd(&lh[bk], 1);
        pairs[lbase[bk] + r] = (unsigned int)src[e] | ((unsigned int)(d & 255) << 17);
    }
}

// ---------------- Pass D: per-bucket fine sort + dinv + csr_off ----------------
__global__ __launch_bounds__(256) void k_fine(const unsigned int* __restrict__ pairs,
                                              const int* __restrict__ boff,
                                              int* __restrict__ csr_off,
                                              int* __restrict__ csr_src,
                                              float* __restrict__ dinv) {
    __shared__ int lcnt[256];
    __shared__ int sc[256];
    __shared__ int lofs[256];
    int t = threadIdx.x;
    int b = blockIdx.x;
    int n0 = b << 8;
    int nnode = min(256, NN - n0);
    int bO = boff[b], bE = boff[b + 1];

    lcnt[t] = 0;
    __syncthreads();
    for (int e = bO + t; e < bE; e += 256)
        atomicAdd(&lcnt[pairs[e] >> 17], 1);
    __syncthreads();
    sc[t] = lcnt[t];
    __syncthreads();
    for (int d = 1; d < 256; d <<= 1) {
        int x = (t >= d) ? sc[t - d] : 0;
        __syncthreads();
        sc[t] += x;
        __syncthreads();
    }
    {
        int excl = sc[t] - lcnt[t];
        lofs[t] = excl;
        if (t < nnode) {
            int n = n0 + t;
            csr_off[n] = bO + excl;
            dinv[n] = rsqrtf(1.0f + (float)lcnt[t]);
        }
        lcnt[t] = 0;   // reuse as cursor
    }
    if (b == NB - 1 && t == 0) csr_off[NN] = NE;
    __syncthreads();
    for (int e = bO + t; e < bE; e += 256) {
        unsigned int w = pairs[e];
        int li = (int)(w >> 17);
        int r = atomicAdd(&lcnt[li], 1);
        csr_src[bO + lofs[li] + r] = (int)(w & 0x1FFFFu);
    }
}

// ---------------- gather1: h1b = bf16( dinv[n]*relu( dinv[n]*acc + b1 ) ) ----------------
__global__ __launch_bounds__(256) void k_gather8(const int* __restrict__ off,
                                                 const int* __restrict__ csr,
                                                 const float* __restrict__ dinv,
                                                 const unsigned short* __restrict__ hb,
                                                 const float* __restrict__ bias,
                                                 unsigned int* __restrict__ outp) {
    int idx = blockIdx.x * 256 + threadIdx.x;   // 8 lanes per node
    int n = idx >> 3;
    if (n >= NN) return;
    int c8 = idx & 7;                           // channels c8*8 .. c8*8+7
    const uint4* h4 = (const uint4*)hb;         // row stride = 8 uint4 (64 bf16)
    float dn = dinv[n];
    float a0[8], a1[8];
    {
        uint4 v = h4[(size_t)n * 8 + c8];       // self term: dn * t1[n]
        a0[0] = dn * bf_lo(v.x); a0[1] = dn * bf_hi(v.x);
        a0[2] = dn * bf_lo(v.y); a0[3] = dn * bf_hi(v.y);
        a0[4] = dn * bf_lo(v.z); a0[5] = dn * bf_hi(v.z);
        a0[6] = dn * bf_lo(v.w); a0[7] = dn * bf_hi(v.w);
        #pragma unroll
        for (int j = 0; j < 8; ++j) a1[j] = 0.f;
    }
    int b = off[n], e = off[n + 1];
    int i = b;
    for (; i + 1 < e; i += 2) {                 // 2-edge unroll, dual accumulators
        int s0 = csr[i], s1 = csr[i + 1];
        float w0 = dinv[s0], w1 = dinv[s1];
        uint4 v0 = h4[(size_t)s0 * 8 + c8];
        uint4 v1 = h4[(size_t)s1 * 8 + c8];
        a0[0] += w0 * bf_lo(v0.x); a0[1] += w0 * bf_hi(v0.x);
        a0[2] += w0 * bf_lo(v0.y); a0[3] += w0 * bf_hi(v0.y);
        a0[4] += w0 * bf_lo(v0.z); a0[5] += w0 * bf_hi(v0.z);
        a0[6] += w0 * bf_lo(v0.w); a0[7] += w0 * bf_hi(v0.w);
        a1[0] += w1 * bf_lo(v1.x); a1[1] += w1 * bf_hi(v1.x);
        a1[2] += w1 * bf_lo(v1.y); a1[3] += w1 * bf_hi(v1.y);
        a1[4] += w1 * bf_lo(v1.z); a1[5] += w1 * bf_hi(v1.z);
        a1[6] += w1 * bf_lo(v1.w); a1[7] += w1 * bf_hi(v1.w);
    }
    if (i < e) {
        int s = csr[i];
        float w = dinv[s];
        uint4 v = h4[(size_t)s * 8 + c8];
        a0[0] += w * bf_lo(v.x); a0[1] += w * bf_hi(v.x);
        a0[2] += w * bf_lo(v.y); a0[3] += w * bf_hi(v.y);
        a0[4] += w * bf_lo(v.z); a0[5] += w * bf_hi(v.z);
        a0[6] += w * bf_lo(v.w); a0[7] += w * bf_hi(v.w);
    }
    float4 b0 = ((const float4*)bias)[c8 * 2];
    float4 b1v = ((const float4*)bias)[c8 * 2 + 1];
    float o[8];
    o[0] = dn * fmaxf(dn * (a0[0] + a1[0]) + b0.x, 0.f);
    o[1] = dn * fmaxf(dn * (a0[1] + a1[1]) + b0.y, 0.f);
    o[2] = dn * fmaxf(dn * (a0[2] + a1[2]) + b0.z, 0.f);
    o[3] = dn * fmaxf(dn * (a0[3] + a1[3]) + b0.w, 0.f);
    o[4] = dn * fmaxf(dn * (a0[4] + a1[4]) + b1v.x, 0.f);
    o[5] = dn * fmaxf(dn * (a0[5] + a1[5]) + b1v.y, 0.f);
    o[6] = dn * fmaxf(dn * (a0[6] + a1[6]) + b1v.z, 0.f);
    o[7] = dn * fmaxf(dn * (a0[7] + a1[7]) + b1v.w, 0.f);
    uint4 p;
    p.x = (unsigned int)f2bf(o[0]) | ((unsigned int)f2bf(o[1]) << 16);
    p.y = (unsigned int)f2bf(o[2]) | ((unsigned int)f2bf(o[3]) << 16);
    p.z = (unsigned int)f2bf(o[4]) | ((unsigned int)f2bf(o[5]) << 16);
    p.w = (unsigned int)f2bf(o[6]) | ((unsigned int)f2bf(o[7]) << 16);
    ((uint4*)outp)[(size_t)n * 8 + c8] = p;
}

// ---------------- GEMM23 (MFMA): y = h1' @ [W2|W3]   [NN,64]x[64,64] ----------------
__global__ __launch_bounds__(512) void k_gemm23(const unsigned short* __restrict__ h1b,
                                                const unsigned short* __restrict__ wt2,
                                                unsigned short* __restrict__ y) {
    __shared__ __align__(16) unsigned short lx[128 * 72];
    __shared__ __align__(16) unsigned short lw[64 * 72];
    const int t = threadIdx.x;
    const int row0 = blockIdx.x * 128;
    const int nrows = min(128, NN - row0);

    #pragma unroll
    for (int i = 0; i < 2; ++i) {
        int f = t + i * 512;            // 0..1023
        int r = f >> 3, c8 = f & 7;
        uint4 v = make_uint4(0u, 0u, 0u, 0u);
        if (r < nrows) v = ((const uint4*)h1b)[(size_t)(row0 + r) * 8 + c8];
        *(uint4*)&lx[r * 72 + c8 * 8] = v;
    }
    if (t < 512) {
        int c = t >> 3, c8 = t & 7;
        uint4 v = ((const uint4*)wt2)[t];
        *(uint4*)&lw[c * 72 + c8 * 8] = v;
    }
    __syncthreads();

    const int w = t >> 6, l = t & 63;
    const int m15 = l & 15, kg = l >> 4;
    const unsigned short* pa = &lx[(w * 16 + m15) * 72 + kg * 8];
    const unsigned short* pb = &lw[m15 * 72 + kg * 8];

    float4_t acc[4];
    #pragma unroll
    for (int cb = 0; cb < 4; ++cb) acc[cb] = (float4_t){0.f, 0.f, 0.f, 0.f};

    #pragma unroll
    for (int ks = 0; ks < 2; ++ks) {
        short8_t a = *(const short8_t*)(pa + ks * 32);
        #pragma unroll
        for (int cb = 0; cb < 4; ++cb) {
            short8_t bb = *(const short8_t*)(pb + cb * (16 * 72) + ks * 32);
            acc[cb] = __builtin_amdgcn_mfma_f32_16x16x32_bf16(a, bb, acc[cb], 0, 0, 0);
        }
    }

    #pragma unroll
    for (int r = 0; r < 4; ++r) {
        int lrow = w * 16 + kg * 4 + r;
        if (lrow < nrows) {
            size_t grow = (size_t)(row0 + lrow);
            #pragma unroll
            for (int cb = 0; cb < 4; ++cb)
                y[grow * 64 + cb * 16 + m15] = f2bf(acc[cb][r]);
        }
    }
}

// ---------------- gatherO: out[n] = dinv[n]*(y[n] + sum_e y[s]) + bias ----------------
__global__ __launch_bounds__(256) void k_gatherO(const int* __restrict__ off,
                                                 const int* __restrict__ csr,
                                                 const float* __restrict__ dinv,
                                                 const unsigned short* __restrict__ yb,
                                                 const float* __restrict__ b2,
                                                 const float* __restrict__ b3,
                                                 float* __restrict__ out) {
    int idx = blockIdx.x * 256 + threadIdx.x;   // NN*8 == 3125*256 exactly
    int n = idx >> 3;
    int c8 = idx & 7;
    const uint4* h4 = (const uint4*)yb;
    float a0[8], a1[8];
    {
        uint4 v = h4[(size_t)n * 8 + c8];       // self term
        a0[0] = bf_lo(v.x); a0[1] = bf_hi(v.x);
        a0[2] = bf_lo(v.y); a0[3] = bf_hi(v.y);
        a0[4] = bf_lo(v.z); a0[5] = bf_hi(v.z);
        a0[6] = bf_lo(v.w); a0[7] = bf_hi(v.w);
        #pragma unroll
        for (int j = 0; j < 8; ++j) a1[j] = 0.f;
    }
    int b = off[n], e = off[n + 1];
    int i = b;
    for (; i + 1 < e; i += 2) {                 // 2-edge unroll, dual accumulators
        int s0 = csr[i], s1 = csr[i + 1];
        uint4 v0 = h4[(size_t)s0 * 8 + c8];
        uint4 v1 = h4[(size_t)s1 * 8 + c8];
        a0[0] += bf_lo(v0.x); a0[1] += bf_hi(v0.x);
        a0[2] += bf_lo(v0.y); a0[3] += bf_hi(v0.y);
        a0[4] += bf_lo(v0.z); a0[5] += bf_hi(v0.z);
        a0[6] += bf_lo(v0.w); a0[7] += bf_hi(v0.w);
        a1[0] += bf_lo(v1.x); a1[1] += bf_hi(v1.x);
        a1[2] += bf_lo(v1.y); a1[3] += bf_hi(v1.y);
        a1[4] += bf_lo(v1.z); a1[5] += bf_hi(v1.z);
        a1[6] += bf_lo(v1.w); a1[7] += bf_hi(v1.w);
    }
    if (i < e) {
        uint4 v = h4[(size_t)csr[i] * 8 + c8];
        a0[0] += bf_lo(v.x); a0[1] += bf_hi(v.x);
        a0[2] += bf_lo(v.y); a0[3] += bf_hi(v.y);
        a0[4] += bf_lo(v.z); a0[5] += bf_hi(v.z);
        a0[6] += bf_lo(v.w); a0[7] += bf_hi(v.w);
    }
    float dn = dinv[n];
    const float* bp = (c8 < 4) ? (b2 + c8 * 8) : (b3 + (c8 - 4) * 8);
    float4 q0 = *(const float4*)bp;
    float4 q1 = *(const float4*)(bp + 4);
    float4 o0, o1;
    o0.x = dn * (a0[0] + a1[0]) + q0.x;
    o0.y = dn * (a0[1] + a1[1]) + q0.y;
    o0.z = dn * (a0[2] + a1[2]) + q0.z;
    o0.w = dn * (a0[3] + a1[3]) + q0.w;
    o1.x = dn * (a0[4] + a1[4]) + q1.x;
    o1.y = dn * (a0[5] + a1[5]) + q1.y;
    o1.z = dn * (a0[6] + a1[6]) + q1.z;
    o1.w = dn * (a0[7] + a1[7]) + q1.w;
    float* op = (c8 < 4) ? (out + (size_t)n * 32 + c8 * 8)
                         : (out + (size_t)NN * 32 + (size_t)n * 32 + (c8 - 4) * 8);
    *(float4*)op = o0;
    *(float4*)(op + 4) = o1;
}

extern "C" void kernel_launch(void* const* d_in, const int* in_sizes, int n_in,
                              void* d_out, int out_size, void* d_ws, size_t ws_size,
                              hipStream_t stream) {
    const float* x  = (const float*)d_in[0];
    const int* edges = (const int*)d_in[1];
    const float* W1 = (const float*)d_in[2];
    const float* b1 = (const float*)d_in[3];
    const float* W2 = (const float*)d_in[4];
    const float* b2 = (const float*)d_in[5];
    const float* W3 = (const float*)d_in[6];
    const float* b3 = (const float*)d_in[7];
    float* out = (float*)d_out;

    const int* srcs = edges;            // edges[0]
    const int* dsts = edges + NE;       // edges[1]

    // ws layout (4-byte words), total 8,204,896 words = 32.8 MB.
    // ALIGNMENT INVARIANT: feature arrays (wtb, t1b/y, pairs/h1b) at offsets
    // that are multiples of 32 words (128 B) so 128-B rows never straddle granules.
    int*   csr_off = (int*)d_ws;                    // [NN+1]
    float* dinv    = (float*)((int*)d_ws + 100004); // [NN]
    int*   csr_src = (int*)d_ws + 200004;           // [NE]
    int*   colsum  = (int*)d_ws + 1800004;          // [NB]
    int*   boff    = (int*)d_ws + 1800396;          // [NB+1]
    unsigned short* wtb = (unsigned short*)((int*)d_ws + 1800800); // [64*128] bf16
    // region A: t1b [NN*64] bf16 (written by k_gemm1); reused as y after gather8
    unsigned short* t1b = (unsigned short*)((int*)d_ws + 1804896); // 128B-aligned
    unsigned short* y   = t1b;          // t1b dead after k_gather8
    // region B: pairs [NE uint] + hist2d/base2d behind it; then h1b (all dead
    // before h1b's first write in k_gather8).
    unsigned int*   pairs  = (unsigned int*)((int*)d_ws + 5004896); // 128B-aligned
    int*            hist2d = (int*)d_ws + 5004896 + 1600000;        // [NB*NB]
    int*            base2d = (int*)d_ws + 5004896 + 1752896;        // [NB*NB]
    unsigned short* h1b    = (unsigned short*)pairs;                // [NN*64] bf16
    // wt2 [64*64] bf16 (8 KB) staged in d_out tail: read by k_gemm23, then
    // fully overwritten by k_gatherO (stream-ordered) — zero ws growth.
    unsigned short* wt2 = (unsigned short*)(out + 6400000 - 2048);

    dim3 blk(256);
    const int gN8 = (NN * 8 + 255) / 256;   // 3125 (exact)
    const int gT1 = (NN + 127) / 128;       // 782
    const int gT23 = (NN + 127) / 128;      // 782

    // prologue: W transposes; deterministic sort offsets (no global atomics)
    k_pre<<<32, blk, 0, stream>>>(W1, W2, W3, wtb, wt2);
    k_chist<<<NCHUNK, blk, 0, stream>>>(dsts, hist2d);
    k_scancol<<<NB, blk, 0, stream>>>(hist2d, base2d, colsum);
    k_scanb<<<1, blk, 0, stream>>>(colsum, boff);

    // split (was fused): GEMM1 then bscatter — separate counter rows
    k_gemm1<<<gT1, dim3(512), 0, stream>>>(x, wtb, t1b);
    k_bscatter<<<NCHUNK, dim3(512), 0, stream>>>(srcs, dsts, base2d, boff, pairs);

    k_fine<<<NB, blk, 0, stream>>>(pairs, boff, csr_off, csr_src, dinv);

    // conv1 aggregation: h1b = bf16(dinv*relu(dinv*Agg(t1)+b1))
    k_gather8<<<gN8, blk, 0, stream>>>(csr_off, csr_src, dinv, t1b, b1,
                                       (unsigned int*)h1b);
    // conv2/3: y = h1' @ [W2|W3] (MFMA), then thin gather to d_out
    k_gemm23<<<gT23, dim3(512), 0, stream>>>(h1b, wt2, y);
    k_gatherO<<<gN8, blk, 0, stream>>>(csr_off, csr_src, dinv, y, b2, b3, out);
}

// Round 20
// 148.333 us; speedup vs baseline: 1.0567x; 1.0567x over previous
//
// GCNEncoder MI355X kernel — v17: v15 fused structure (gemm1 ∥ bscatter, ~7 µs
// overlap proven by v16 split) + v16's reg-staged A-loads + launch_bounds(512,8)
// (64 VGPR: 8 float4 in flight vs v15's 2 at VGPR=32). Rest identical to v15.
#include <hip/hip_runtime.h>

#define NN 100000
#define NE 1600000
#define NB 391            // ceil(NN/256) buckets of 256 nodes (bucket = dst >> 8)
#define CHUNK 4096
#define NCHUNK 391        // ceil(NE/CHUNK)

typedef __attribute__((ext_vector_type(8))) short short8_t;
typedef __attribute__((ext_vector_type(4))) float float4_t;

// ---- bf16 helpers (RNE pack, bit-op unpack) ----
__device__ inline unsigned short f2bf(float f) {
    unsigned int u = __float_as_uint(f);
    unsigned int r = u + 0x7fffu + ((u >> 16) & 1u);
    return (unsigned short)(r >> 16);
}
__device__ inline float bf_lo(unsigned int u) { return __uint_as_float(u << 16); }
__device__ inline float bf_hi(unsigned int u) { return __uint_as_float(u & 0xffff0000u); }

// ---------------- prologue: W1^T, [W2|W3]^T ----------------
__global__ __launch_bounds__(256) void k_pre(const float* __restrict__ W1,
                                             const float* __restrict__ W2,
                                             const float* __restrict__ W3,
                                             unsigned short* __restrict__ wtb,
                                             unsigned short* __restrict__ wt2) {
    int f = blockIdx.x * 256 + threadIdx.x;      // 0..8191
    int c = f >> 7, k = f & 127;
    wtb[f] = f2bf(W1[k * 64 + c]);               // wtb[c][k] = W1[k][c]
    if (f < 4096) {                              // wt2[c][k] = Wc[k][c], Wc=[W2|W3]
        int c2 = f >> 6, k2 = f & 63;
        float v = (c2 < 32) ? W2[k2 * 32 + c2] : W3[k2 * 32 + (c2 - 32)];
        wt2[f] = f2bf(v);
    }
}

// ---------------- per-chunk histogram: hist2d[c][b] ----------------
__global__ __launch_bounds__(256) void k_chist(const int* __restrict__ dst,
                                               int* __restrict__ hist2d) {
    __shared__ int lh[NB];
    int c = blockIdx.x, t = threadIdx.x;
    for (int i = t; i < NB; i += 256) lh[i] = 0;
    __syncthreads();
    int e0 = c * CHUNK, e1 = min(e0 + CHUNK, NE);
    for (int e = e0 + t; e < e1; e += 256)
        atomicAdd(&lh[dst[e] >> 8], 1);
    __syncthreads();
    for (int i = t; i < NB; i += 256) hist2d[c * NB + i] = lh[i];
}

// ---------------- per-bucket scan over chunks: base2d[c][b], colsum[b] ----------------
__global__ __launch_bounds__(256) void k_scancol(const int* __restrict__ hist2d,
                                                 int* __restrict__ base2d,
                                                 int* __restrict__ colsum) {
    __shared__ int sh[256];
    int b = blockIdx.x, t = threadIdx.x;
    int base = t * 2;                       // chunks base, base+1
    int v0 = (base + 0 < NCHUNK) ? hist2d[(base + 0) * NB + b] : 0;
    int v1 = (base + 1 < NCHUNK) ? hist2d[(base + 1) * NB + b] : 0;
    int tsum = v0 + v1;
    sh[t] = tsum;
    __syncthreads();
    for (int d = 1; d < 256; d <<= 1) {
        int x = (t >= d) ? sh[t - d] : 0;
        __syncthreads();
        sh[t] += x;
        __syncthreads();
    }
    int excl = sh[t] - tsum;
    if (base + 0 < NCHUNK) base2d[(base + 0) * NB + b] = excl;
    if (base + 1 < NCHUNK) base2d[(base + 1) * NB + b] = excl + v0;
    if (t == 255) colsum[b] = sh[255];
}

// ---------------- bucket scan: boff ----------------
__global__ __launch_bounds__(256) void k_scanb(const int* __restrict__ colsum,
                                               int* __restrict__ boff) {
    __shared__ int sh[256];
    int t = threadIdx.x;
    int base = t * 2;
    int v0 = (base + 0 < NB) ? colsum[base + 0] : 0;
    int v1 = (base + 1 < NB) ? colsum[base + 1] : 0;
    int tsum = v0 + v1;
    sh[t] = tsum;
    __syncthreads();
    for (int d = 1; d < 256; d <<= 1) {
        int x = (t >= d) ? sh[t - d] : 0;
        __syncthreads();
        sh[t] += x;
        __syncthreads();
    }
    int excl = sh[t] - tsum;
    if (base + 0 < NB) boff[base + 0] = excl;
    if (base + 1 < NB) boff[base + 1] = excl + v0;
    if (t == 255) boff[NB] = sh[255];   // == NE
}

// ---------------- FUSED: GEMM1 (MFMA, reg-staged A) ∥ bscatter (atomic-free) ----------------
// blocks: b%3==2 -> bscatter chunk b/3 (391); else gemm1 tile 2*(b/3)+(b%3) (782).
__global__ __launch_bounds__(512, 8) void k_fuse(const float* __restrict__ x,
                                                 const unsigned short* __restrict__ wtb,
                                                 unsigned short* __restrict__ t1b,
                                                 const int* __restrict__ src,
                                                 const int* __restrict__ dst,
                                                 const int* __restrict__ base2d,
                                                 const int* __restrict__ boff,
                                                 unsigned int* __restrict__ pairs) {
    __shared__ int sbuf[2 * NB];       // bscatter role only (3.1 KB)
    const int b = blockIdx.x;
    const int t = threadIdx.x;

    if ((b % 3) == 2) {
        // ---- bscatter role: precomputed bases, LDS cursor only ----
        int* lbase = sbuf;                // [NB]
        int* lh    = sbuf + NB;           // [NB]
        const int c = b / 3;
        int e0 = c * CHUNK;
        int e1 = min(e0 + CHUNK, NE);
        for (int i = t; i < NB; i += 512) {
            lbase[i] = base2d[c * NB + i] + boff[i];
            lh[i] = 0;
        }
        __syncthreads();
        for (int e = e0 + t; e < e1; e += 512) {
            int d = dst[e];
            int bk = d >> 8;
            int r = atomicAdd(&lh[bk], 1);
            pairs[lbase[bk] + r] = (unsigned int)src[e] | ((unsigned int)(d & 255) << 17);
        }
    } else {
        // ---- gemm1 role: no LDS, no barrier, reg-staged A ----
        const int tile = 2 * (b / 3) + (b % 3);
        const int row0 = tile * 128;
        const int nrows = min(128, NN - row0);
        const int w = t >> 6, l = t & 63;
        const int m15 = l & 15, kg = l >> 4;

        int ra = min(row0 + w * 16 + m15, NN - 1);   // clamped tail row
        const float4* xa = (const float4*)(x + (size_t)ra * 128) + kg * 2;

        // stage ALL 8 x-loads into registers first -> 8 loads in flight per wave
        float4 f[8];
        #pragma unroll
        for (int ks = 0; ks < 4; ++ks) {
            f[2 * ks]     = xa[ks * 8];
            f[2 * ks + 1] = xa[ks * 8 + 1];
        }

        float4_t acc[4];
        #pragma unroll
        for (int cb = 0; cb < 4; ++cb) acc[cb] = (float4_t){0.f, 0.f, 0.f, 0.f};

        #pragma unroll
        for (int ks = 0; ks < 4; ++ks) {
            float4 f0 = f[2 * ks], f1 = f[2 * ks + 1];
            short8_t a;
            a[0] = (short)f2bf(f0.x); a[1] = (short)f2bf(f0.y);
            a[2] = (short)f2bf(f0.z); a[3] = (short)f2bf(f0.w);
            a[4] = (short)f2bf(f1.x); a[5] = (short)f2bf(f1.y);
            a[6] = (short)f2bf(f1.z); a[7] = (short)f2bf(f1.w);
            #pragma unroll
            for (int cb = 0; cb < 4; ++cb) {
                short8_t bb = *(const short8_t*)(wtb + (cb * 16 + m15) * 128 + ks * 32 + kg * 8);
                acc[cb] = __builtin_amdgcn_mfma_f32_16x16x32_bf16(a, bb, acc[cb], 0, 0, 0);
            }
        }

        #pragma unroll
        for (int r = 0; r < 4; ++r) {
            int lrow = w * 16 + kg * 4 + r;
            if (lrow < nrows) {
                size_t grow = (size_t)(row0 + lrow);
                #pragma unroll
                for (int cb = 0; cb < 4; ++cb)
                    t1b[grow * 64 + cb * 16 + m15] = f2bf(acc[cb][r]);
            }
        }
    }
}

// ---------------- Pass D: per-bucket fine sort + dinv + csr_off ----------------
__global__ __launch_bounds__(256) void k_fine(const unsigned int* __restrict__ pairs,
                                              const int* __restrict__ boff,
                                              int* __restrict__ csr_off,
                                              int* __restrict__ csr_src,
                                              float* __restrict__ dinv) {
    __shared__ int lcnt[256];
    __shared__ int sc[256];
    __shared__ int lofs[256];
    int t = threadIdx.x;
    int b = blockIdx.x;
    int n0 = b << 8;
    int nnode = min(256, NN - n0);
    int bO = boff[b], bE = boff[b + 1];

    lcnt[t] = 0;
    __syncthreads();
    for (int e = bO + t; e < bE; e += 256)
        atomicAdd(&lcnt[pairs[e] >> 17], 1);
    __syncthreads();
    sc[t] = lcnt[t];
    __syncthreads();
    for (int d = 1; d < 256; d <<= 1) {
        int x = (t >= d) ? sc[t - d] : 0;
        __syncthreads();
        sc[t] += x;
        __syncthreads();
    }
    {
        int excl = sc[t] - lcnt[t];
        lofs[t] = excl;
        if (t < nnode) {
            int n = n0 + t;
            csr_off[n] = bO + excl;
            dinv[n] = rsqrtf(1.0f + (float)lcnt[t]);
        }
        lcnt[t] = 0;   // reuse as cursor
    }
    if (b == NB - 1 && t == 0) csr_off[NN] = NE;
    __syncthreads();
    for (int e = bO + t; e < bE; e += 256) {
        unsigned int w = pairs[e];
        int li = (int)(w >> 17);
        int r = atomicAdd(&lcnt[li], 1);
        csr_src[bO + lofs[li] + r] = (int)(w & 0x1FFFFu);
    }
}

// ---------------- gather1: h1b = bf16( dinv[n]*relu( dinv[n]*acc + b1 ) ) ----------------
__global__ __launch_bounds__(256) void k_gather8(const int* __restrict__ off,
                                                 const int* __restrict__ csr,
                                                 const float* __restrict__ dinv,
                                                 const unsigned short* __restrict__ hb,
                                                 const float* __restrict__ bias,
                                                 unsigned int* __restrict__ outp) {
    int idx = blockIdx.x * 256 + threadIdx.x;   // 8 lanes per node
    int n = idx >> 3;
    if (n >= NN) return;
    int c8 = idx & 7;                           // channels c8*8 .. c8*8+7
    const uint4* h4 = (const uint4*)hb;         // row stride = 8 uint4 (64 bf16)
    float dn = dinv[n];
    float a0[8], a1[8];
    {
        uint4 v = h4[(size_t)n * 8 + c8];       // self term: dn * t1[n]
        a0[0] = dn * bf_lo(v.x); a0[1] = dn * bf_hi(v.x);
        a0[2] = dn * bf_lo(v.y); a0[3] = dn * bf_hi(v.y);
        a0[4] = dn * bf_lo(v.z); a0[5] = dn * bf_hi(v.z);
        a0[6] = dn * bf_lo(v.w); a0[7] = dn * bf_hi(v.w);
        #pragma unroll
        for (int j = 0; j < 8; ++j) a1[j] = 0.f;
    }
    int b = off[n], e = off[n + 1];
    int i = b;
    for (; i + 1 < e; i += 2) {                 // 2-edge unroll, dual accumulators
        int s0 = csr[i], s1 = csr[i + 1];
        float w0 = dinv[s0], w1 = dinv[s1];
        uint4 v0 = h4[(size_t)s0 * 8 + c8];
        uint4 v1 = h4[(size_t)s1 * 8 + c8];
        a0[0] += w0 * bf_lo(v0.x); a0[1] += w0 * bf_hi(v0.x);
        a0[2] += w0 * bf_lo(v0.y); a0[3] += w0 * bf_hi(v0.y);
        a0[4] += w0 * bf_lo(v0.z); a0[5] += w0 * bf_hi(v0.z);
        a0[6] += w0 * bf_lo(v0.w); a0[7] += w0 * bf_hi(v0.w);
        a1[0] += w1 * bf_lo(v1.x); a1[1] += w1 * bf_hi(v1.x);
        a1[2] += w1 * bf_lo(v1.y); a1[3] += w1 * bf_hi(v1.y);
        a1[4] += w1 * bf_lo(v1.z); a1[5] += w1 * bf_hi(v1.z);
        a1[6] += w1 * bf_lo(v1.w); a1[7] += w1 * bf_hi(v1.w);
    }
    if (i < e) {
        int s = csr[i];
        float w = dinv[s];
        uint4 v = h4[(size_t)s * 8 + c8];
        a0[0] += w * bf_lo(v.x); a0[1] += w * bf_hi(v.x);
        a0[2] += w * bf_lo(v.y); a0[3] += w * bf_hi(v.y);
        a0[4] += w * bf_lo(v.z); a0[5] += w * bf_hi(v.z);
        a0[6] += w * bf_lo(v.w); a0[7] += w * bf_hi(v.w);
    }
    float4 b0 = ((const float4*)bias)[c8 * 2];
    float4 b1v = ((const float4*)bias)[c8 * 2 + 1];
    float o[8];
    o[0] = dn * fmaxf(dn * (a0[0] + a1[0]) + b0.x, 0.f);
    o[1] = dn * fmaxf(dn * (a0[1] + a1[1]) + b0.y, 0.f);
    o[2] = dn * fmaxf(dn * (a0[2] + a1[2]) + b0.z, 0.f);
    o[3] = dn * fmaxf(dn * (a0[3] + a1[3]) + b0.w, 0.f);
    o[4] = dn * fmaxf(dn * (a0[4] + a1[4]) + b1v.x, 0.f);
    o[5] = dn * fmaxf(dn * (a0[5] + a1[5]) + b1v.y, 0.f);
    o[6] = dn * fmaxf(dn * (a0[6] + a1[6]) + b1v.z, 0.f);
    o[7] = dn * fmaxf(dn * (a0[7] + a1[7]) + b1v.w, 0.f);
    uint4 p;
    p.x = (unsigned int)f2bf(o[0]) | ((unsigned int)f2bf(o[1]) << 16);
    p.y = (unsigned int)f2bf(o[2]) | ((unsigned int)f2bf(o[3]) << 16);
    p.z = (unsigned int)f2bf(o[4]) | ((unsigned int)f2bf(o[5]) << 16);
    p.w = (unsigned int)f2bf(o[6]) | ((unsigned int)f2bf(o[7]) << 16);
    ((uint4*)outp)[(size_t)n * 8 + c8] = p;
}

// ---------------- GEMM23 (MFMA): y = h1' @ [W2|W3]   [NN,64]x[64,64] ----------------
__global__ __launch_bounds__(512) void k_gemm23(const unsigned short* __restrict__ h1b,
                                                const unsigned short* __restrict__ wt2,
                                                unsigned short* __restrict__ y) {
    __shared__ __align__(16) unsigned short lx[128 * 72];
    __shared__ __align__(16) unsigned short lw[64 * 72];
    const int t = threadIdx.x;
    const int row0 = blockIdx.x * 128;
    const int nrows = min(128, NN - row0);

    #pragma unroll
    for (int i = 0; i < 2; ++i) {
        int f = t + i * 512;            // 0..1023
        int r = f >> 3, c8 = f & 7;
        uint4 v = make_uint4(0u, 0u, 0u, 0u);
        if (r < nrows) v = ((const uint4*)h1b)[(size_t)(row0 + r) * 8 + c8];
        *(uint4*)&lx[r * 72 + c8 * 8] = v;
    }
    if (t < 512) {
        int c = t >> 3, c8 = t & 7;
        uint4 v = ((const uint4*)wt2)[t];
        *(uint4*)&lw[c * 72 + c8 * 8] = v;
    }
    __syncthreads();

    const int w = t >> 6, l = t & 63;
    const int m15 = l & 15, kg = l >> 4;
    const unsigned short* pa = &lx[(w * 16 + m15) * 72 + kg * 8];
    const unsigned short* pb = &lw[m15 * 72 + kg * 8];

    float4_t acc[4];
    #pragma unroll
    for (int cb = 0; cb < 4; ++cb) acc[cb] = (float4_t){0.f, 0.f, 0.f, 0.f};

    #pragma unroll
    for (int ks = 0; ks < 2; ++ks) {
        short8_t a = *(const short8_t*)(pa + ks * 32);
        #pragma unroll
        for (int cb = 0; cb < 4; ++cb) {
            short8_t bb = *(const short8_t*)(pb + cb * (16 * 72) + ks * 32);
            acc[cb] = __builtin_amdgcn_mfma_f32_16x16x32_bf16(a, bb, acc[cb], 0, 0, 0);
        }
    }

    #pragma unroll
    for (int r = 0; r < 4; ++r) {
        int lrow = w * 16 + kg * 4 + r;
        if (lrow < nrows) {
            size_t grow = (size_t)(row0 + lrow);
            #pragma unroll
            for (int cb = 0; cb < 4; ++cb)
                y[grow * 64 + cb * 16 + m15] = f2bf(acc[cb][r]);
        }
    }
}

// ---------------- gatherO: out[n] = dinv[n]*(y[n] + sum_e y[s]) + bias ----------------
__global__ __launch_bounds__(256) void k_gatherO(const int* __restrict__ off,
                                                 const int* __restrict__ csr,
                                                 const float* __restrict__ dinv,
                                                 const unsigned short* __restrict__ yb,
                                                 const float* __restrict__ b2,
                                                 const float* __restrict__ b3,
                                                 float* __restrict__ out) {
    int idx = blockIdx.x * 256 + threadIdx.x;   // NN*8 == 3125*256 exactly
    int n = idx >> 3;
    int c8 = idx & 7;
    const uint4* h4 = (const uint4*)yb;
    float a0[8], a1[8];
    {
        uint4 v = h4[(size_t)n * 8 + c8];       // self term
        a0[0] = bf_lo(v.x); a0[1] = bf_hi(v.x);
        a0[2] = bf_lo(v.y); a0[3] = bf_hi(v.y);
        a0[4] = bf_lo(v.z); a0[5] = bf_hi(v.z);
        a0[6] = bf_lo(v.w); a0[7] = bf_hi(v.w);
        #pragma unroll
        for (int j = 0; j < 8; ++j) a1[j] = 0.f;
    }
    int b = off[n], e = off[n + 1];
    int i = b;
    for (; i + 1 < e; i += 2) {                 // 2-edge unroll, dual accumulators
        int s0 = csr[i], s1 = csr[i + 1];
        uint4 v0 = h4[(size_t)s0 * 8 + c8];
        uint4 v1 = h4[(size_t)s1 * 8 + c8];
        a0[0] += bf_lo(v0.x); a0[1] += bf_hi(v0.x);
        a0[2] += bf_lo(v0.y); a0[3] += bf_hi(v0.y);
        a0[4] += bf_lo(v0.z); a0[5] += bf_hi(v0.z);
        a0[6] += bf_lo(v0.w); a0[7] += bf_hi(v0.w);
        a1[0] += bf_lo(v1.x); a1[1] += bf_hi(v1.x);
        a1[2] += bf_lo(v1.y); a1[3] += bf_hi(v1.y);
        a1[4] += bf_lo(v1.z); a1[5] += bf_hi(v1.z);
        a1[6] += bf_lo(v1.w); a1[7] += bf_hi(v1.w);
    }
    if (i < e) {
        uint4 v = h4[(size_t)csr[i] * 8 + c8];
        a0[0] += bf_lo(v.x); a0[1] += bf_hi(v.x);
        a0[2] += bf_lo(v.y); a0[3] += bf_hi(v.y);
        a0[4] += bf_lo(v.z); a0[5] += bf_hi(v.z);
        a0[6] += bf_lo(v.w); a0[7] += bf_hi(v.w);
    }
    float dn = dinv[n];
    const float* bp = (c8 < 4) ? (b2 + c8 * 8) : (b3 + (c8 - 4) * 8);
    float4 q0 = *(const float4*)bp;
    float4 q1 = *(const float4*)(bp + 4);
    float4 o0, o1;
    o0.x = dn * (a0[0] + a1[0]) + q0.x;
    o0.y = dn * (a0[1] + a1[1]) + q0.y;
    o0.z = dn * (a0[2] + a1[2]) + q0.z;
    o0.w = dn * (a0[3] + a1[3]) + q0.w;
    o1.x = dn * (a0[4] + a1[4]) + q1.x;
    o1.y = dn * (a0[5] + a1[5]) + q1.y;
    o1.z = dn * (a0[6] + a1[6]) + q1.z;
    o1.w = dn * (a0[7] + a1[7]) + q1.w;
    float* op = (c8 < 4) ? (out + (size_t)n * 32 + c8 * 8)
                         : (out + (size_t)NN * 32 + (size_t)n * 32 + (c8 - 4) * 8);
    *(float4*)op = o0;
    *(float4*)(op + 4) = o1;
}

extern "C" void kernel_launch(void* const* d_in, const int* in_sizes, int n_in,
                              void* d_out, int out_size, void* d_ws, size_t ws_size,
                              hipStream_t stream) {
    const float* x  = (const float*)d_in[0];
    const int* edges = (const int*)d_in[1];
    const float* W1 = (const float*)d_in[2];
    const float* b1 = (const float*)d_in[3];
    const float* W2 = (const float*)d_in[4];
    const float* b2 = (const float*)d_in[5];
    const float* W3 = (const float*)d_in[6];
    const float* b3 = (const float*)d_in[7];
    float* out = (float*)d_out;

    const int* srcs = edges;            // edges[0]
    const int* dsts = edges + NE;       // edges[1]

    // ws layout (4-byte words), total 8,204,896 words = 32.8 MB.
    // ALIGNMENT INVARIANT: feature arrays (wtb, t1b/y, pairs/h1b) at offsets
    // that are multiples of 32 words (128 B) so 128-B rows never straddle granules.
    int*   csr_off = (int*)d_ws;                    // [NN+1]
    float* dinv    = (float*)((int*)d_ws + 100004); // [NN]
    int*   csr_src = (int*)d_ws + 200004;           // [NE]
    int*   colsum  = (int*)d_ws + 1800004;          // [NB]
    int*   boff    = (int*)d_ws + 1800396;          // [NB+1]
    unsigned short* wtb = (unsigned short*)((int*)d_ws + 1800800); // [64*128] bf16
    // region A: t1b [NN*64] bf16 (written by k_fuse); reused as y after gather8
    unsigned short* t1b = (unsigned short*)((int*)d_ws + 1804896); // 128B-aligned
    unsigned short* y   = t1b;          // t1b dead after k_gather8
    // region B: pairs [NE uint] + hist2d/base2d behind it; then h1b (all dead
    // before h1b's first write in k_gather8).
    unsigned int*   pairs  = (unsigned int*)((int*)d_ws + 5004896); // 128B-aligned
    int*            hist2d = (int*)d_ws + 5004896 + 1600000;        // [NB*NB]
    int*            base2d = (int*)d_ws + 5004896 + 1752896;        // [NB*NB]
    unsigned short* h1b    = (unsigned short*)pairs;                // [NN*64] bf16
    // wt2 [64*64] bf16 (8 KB) staged in d_out tail: read by k_gemm23, then
    // fully overwritten by k_gatherO (stream-ordered) — zero ws growth.
    unsigned short* wt2 = (unsigned short*)(out + 6400000 - 2048);

    dim3 blk(256);
    const int gN8 = (NN * 8 + 255) / 256;   // 3125 (exact)
    const int gT23 = (NN + 127) / 128;      // 782

    // prologue: W transposes; deterministic sort offsets (no global atomics)
    k_pre<<<32, blk, 0, stream>>>(W1, W2, W3, wtb, wt2);
    k_chist<<<NCHUNK, blk, 0, stream>>>(dsts, hist2d);
    k_scancol<<<NB, blk, 0, stream>>>(hist2d, base2d, colsum);
    k_scanb<<<1, blk, 0, stream>>>(colsum, boff);

    // fused: GEMM1 (782 tiles, reg-staged) ∥ bscatter (391 chunks, atomic-free)
    k_fuse<<<3 * NCHUNK, dim3(512), 0, stream>>>(x, wtb, t1b, srcs, dsts,
                                                 base2d, boff, pairs);

    k_fine<<<NB, blk, 0, stream>>>(pairs, boff, csr_off, csr_src, dinv);

    // conv1 aggregation: h1b = bf16(dinv*relu(dinv*Agg(t1)+b1))
    k_gather8<<<gN8, blk, 0, stream>>>(csr_off, csr_src, dinv, t1b, b1,
                                       (unsigned int*)h1b);
    // conv2/3: y = h1' @ [W2|W3] (MFMA), then thin gather to d_out
    k_gemm23<<<gT23, dim3(512), 0, stream>>>(h1b, wt2, y);
    k_gatherO<<<gN8, blk, 0, stream>>>(csr_off, csr_src, dinv, y, b2, b3, out);
}